// Round 2
// baseline (1028.572 us; speedup 1.0000x reference)
//
#include <hip/hip_runtime.h>
#include <cmath>

#define NNODES 8192
#define NB 64
#define ND 5
#define NF 16
#define NHC 16
#define NE (NNODES*(ND+1))

// ---------------- CSR build (reverse graph: in-edges per dst) ----------------

__global__ void k_count(const int* __restrict__ nbr, int* __restrict__ cnt) {
  int i = blockIdx.x*blockDim.x + threadIdx.x;
  if (i < NNODES*ND) atomicAdd(&cnt[nbr[i]], 1);
}

__global__ void __launch_bounds__(1024)
k_scan(const int* __restrict__ cnt, int* __restrict__ offs, int* __restrict__ cursor) {
  __shared__ int part[1024];
  int t = threadIdx.x;
  const int chunk = NNODES/1024;   // 8
  int base = t*chunk;
  int s = 0;
  for (int i = 0; i < chunk; ++i) s += cnt[base+i] + 1;  // +1 self-loop
  part[t] = s;
  __syncthreads();
  for (int off = 1; off < 1024; off <<= 1) {
    int v = (t >= off) ? part[t-off] : 0;
    __syncthreads();
    part[t] += v;
    __syncthreads();
  }
  int run = (t == 0) ? 0 : part[t-1];
  for (int i = 0; i < chunk; ++i) {
    offs[base+i] = run;
    cursor[base+i] = run;
    run += cnt[base+i] + 1;
  }
  if (t == 1023) offs[NNODES] = run;
}

__global__ void k_fill(const int* __restrict__ nbr, int* __restrict__ cursor, int* __restrict__ srcl) {
  int i = blockIdx.x*blockDim.x + threadIdx.x;
  if (i >= NE) return;
  int u, v;
  if (i < NNODES*ND) { u = i/ND; v = nbr[i]; }
  else               { u = i - NNODES*ND; v = u; }
  int pos = atomicAdd(&cursor[v], 1);
  srcl[pos] = u;
}

// ---------------- reshape x (B,N,16) -> h0 [N][B][16] ----------------

__global__ void k_t0(const float* __restrict__ x, float* __restrict__ h0) {
  int gid = blockIdx.x*blockDim.x + threadIdx.x;
  int n = gid >> 6;
  int b = gid & 63;
  const float4* src = (const float4*)(x + (((size_t)b*NNODES + n) << 4));
  float4* dst = (float4*)(h0 + ((n << 10) + (b << 4)));
  #pragma unroll
  for (int q = 0; q < 4; ++q) dst[q] = src[q];
}

// ---------------- fused GATv2 layer: gather h[u], recompute xl on the fly ----------------
// wave = one dst node v, lane = batch b. Gather of h[u] is a contiguous 4KB/wave.

template<bool LAST>
__global__ void __launch_bounds__(256)
k_layer(const float* __restrict__ hin,
        const float* __restrict__ Wl, const float* __restrict__ Wr,
        const float* __restrict__ att, const float* __restrict__ bias,
        const int* __restrict__ offs, const int* __restrict__ srcl,
        float* __restrict__ hout) {
  int gid = blockIdx.x*blockDim.x + threadIdx.x;
  int v = gid >> 6;
  int b = gid & 63;
  int boff = b << 4;

  // own features -> xr = Wr^T h[v]
  const float4* hp = (const float4*)(hin + ((v << 10) + boff));
  float hv[16];
  #pragma unroll
  for (int q = 0; q < 4; ++q) *(float4*)(hv+4*q) = hp[q];
  float xrv[16];
  #pragma unroll
  for (int j = 0; j < 16; ++j) xrv[j] = 0.f;
  #pragma unroll
  for (int f = 0; f < 16; ++f) {
    float hf = hv[f];
    #pragma unroll
    for (int j = 0; j < 16; ++j) xrv[j] = fmaf(hf, Wr[f*16+j], xrv[j]);
  }

  float s4[4] = {0.f, 0.f, 0.f, 0.f};
  float acc[16];
  #pragma unroll
  for (int j = 0; j < 16; ++j) acc[j] = 0.f;

  int e0 = offs[v], e1 = offs[v+1];
  int u = srcl[e0];
  for (int e = e0; e < e1; ++e) {
    const float4* sp = (const float4*)(hin + ((u << 10) + boff));
    float t[16];
    #pragma unroll
    for (int q = 0; q < 4; ++q) *(float4*)(t+4*q) = sp[q];
    if (e+1 < e1) u = srcl[e+1];          // prefetch next index during compute
    #pragma unroll
    for (int hh = 0; hh < 4; ++hh) {
      // xl[u] for this head, recomputed in-register (saves the xl staging pass)
      float xlu[4] = {0.f, 0.f, 0.f, 0.f};
      #pragma unroll
      for (int f = 0; f < 16; ++f) {
        float tf = t[f];
        #pragma unroll
        for (int c = 0; c < 4; ++c) xlu[c] = fmaf(tf, Wl[f*16 + hh*4 + c], xlu[c]);
      }
      float lg = 0.f;
      #pragma unroll
      for (int c = 0; c < 4; ++c) {
        float z = xlu[c] + xrv[hh*4+c];
        z = (z >= 0.f) ? z : 0.2f*z;       // leaky_relu slope 0.2
        lg = fmaf(z, att[hh*4+c], lg);
      }
      // plain exp-sum softmax (no max-rescale): logits bounded << 88, identical math
      float p = __expf(lg);
      s4[hh] += p;
      #pragma unroll
      for (int c = 0; c < 4; ++c) acc[hh*4+c] = fmaf(p, xlu[c], acc[hh*4+c]);
    }
  }

  float o[16];
  #pragma unroll
  for (int hh = 0; hh < 4; ++hh) {
    float inv = 1.f / s4[hh];
    #pragma unroll
    for (int c = 0; c < 4; ++c) o[hh*4+c] = acc[hh*4+c]*inv + bias[hh*4+c];
  }
  float4* dst = (float4*)(hout + ((v << 10) + boff));
  #pragma unroll
  for (int q = 0; q < 4; ++q) dst[q] = *(float4*)(o+4*q);
  (void)sizeof(LAST);
}

// ---------------- mean over nodes + 2-layer tanh MLP -> agg[B][64] ----------------

__global__ void __launch_bounds__(1024)
k_agg(const float* __restrict__ h, const float* __restrict__ Wg1, const float* __restrict__ bg1,
      const float* __restrict__ Wg2, const float* __restrict__ bg2, float* __restrict__ agg) {
  int b = blockIdx.x;
  int t = threadIdx.x;                 // 1024 threads
  int hc = t & 15, chunk = t >> 4;     // 64 chunks of 128 nodes
  float s = 0.f;
  for (int i = 0; i < NNODES/64; ++i) {
    int n = chunk*(NNODES/64) + i;
    s += h[((size_t)n*NB + b)*NHC + hc];
  }
  __shared__ float red[1024];
  red[t] = s;
  __syncthreads();
  for (int off = 512; off >= 16; off >>= 1) {
    if (t < off) red[t] += red[t+off];
    __syncthreads();
  }
  __shared__ float mean[16], g1[32];
  if (t < 16) mean[t] = red[t] * (1.0f/NNODES);
  __syncthreads();
  if (t < 32) {
    float a = bg1[t];
    for (int f = 0; f < 16; ++f) a = fmaf(mean[f], Wg1[f*32+t], a);
    g1[t] = tanhf(a);
  }
  __syncthreads();
  if (t < 64) {
    float a = bg2[t];
    for (int f = 0; f < 32; ++f) a = fmaf(g1[f], Wg2[f*64+t], a);
    agg[b*64+t] = tanhf(a);
  }
}

// ---------------- final edge-scoring MLP: feats(99) -> 16 -> 8 -> 1 ----------------

__global__ void k_final(const float* __restrict__ h, const int* __restrict__ agent,
                        const int* __restrict__ nbr, const float* __restrict__ agg,
                        const float* __restrict__ We1, const float* __restrict__ be1,
                        const float* __restrict__ We2, const float* __restrict__ be2,
                        const float* __restrict__ We3, const float* __restrict__ be3,
                        float* __restrict__ out) {
  int b = blockIdx.x;
  int t = threadIdx.x;                 // 256
  __shared__ float srcv[16];
  __shared__ float tgt[5][16];
  __shared__ float aggs[64];
  __shared__ float e1s[15][16];
  __shared__ float e2s[15][8];
  int an = agent[b];
  if (t < 16) srcv[t] = h[((size_t)an*NB + b)*NHC + t];
  if (t >= 32 && t < 112) {
    int d = (t-32)/16, k = (t-32)%16;
    int nn = nbr[an*ND + d];
    tgt[d][k] = h[((size_t)nn*NB + b)*NHC + k];
  }
  if (t >= 128 && t < 192) aggs[t-128] = agg[b*64 + (t-128)];
  __syncthreads();
  if (t < 240) {
    int j = t & 15, td = t >> 4;       // td = tk*5+d
    int tk = td/5, d = td%5;
    float a = be1[j];
    for (int k = 0; k < 16; ++k) a = fmaf(srcv[k],  We1[k*16+j],      a);
    a += We1[(16+tk)*16 + j];          // one-hot token rows 16..18
    for (int k = 0; k < 16; ++k) a = fmaf(tgt[d][k], We1[(19+k)*16+j], a);
    for (int k = 0; k < 64; ++k) a = fmaf(aggs[k],  We1[(35+k)*16+j], a);
    e1s[td][j] = tanhf(a);
  }
  __syncthreads();
  if (t < 120) {
    int j = t & 7, td = t >> 3;
    float a = be2[j];
    for (int k = 0; k < 16; ++k) a = fmaf(e1s[td][k], We2[k*8+j], a);
    e2s[td][j] = tanhf(a);
  }
  __syncthreads();
  if (t < 15) {
    float a = be3[0];
    for (int k = 0; k < 8; ++k) a = fmaf(e2s[t][k], We3[k], a);
    out[b*15 + t] = a;
  }
}

// ---------------- launch ----------------

extern "C" void kernel_launch(void* const* d_in, const int* in_sizes, int n_in,
                              void* d_out, int out_size, void* d_ws, size_t ws_size,
                              hipStream_t stream) {
  const float* x     = (const float*)d_in[0];
  const int*   agent = (const int*)  d_in[1];
  const int*   nbr   = (const int*)  d_in[2];
  const float* Wl    = (const float*)d_in[3];   // (4,16,4,4)
  const float* Wr    = (const float*)d_in[4];
  const float* att   = (const float*)d_in[5];   // (4,4,4)
  const float* bias  = (const float*)d_in[6];   // (4,16)
  const float* Wg1   = (const float*)d_in[7];
  const float* bg1   = (const float*)d_in[8];
  const float* Wg2   = (const float*)d_in[9];
  const float* bg2   = (const float*)d_in[10];
  const float* We1   = (const float*)d_in[11];
  const float* be1   = (const float*)d_in[12];
  const float* We2   = (const float*)d_in[13];
  const float* be2   = (const float*)d_in[14];
  const float* We3   = (const float*)d_in[15];
  const float* be3   = (const float*)d_in[16];
  float* out = (float*)d_out;

  char* ws = (char*)d_ws;
  size_t off = 0;
  auto alloc = [&](size_t bytes) -> void* {
    void* p = ws + off;
    off += (bytes + 255) & ~(size_t)255;
    return p;
  };
  const size_t HBYTES = (size_t)NNODES*NB*NHC*sizeof(float);   // 32 MB
  float* hA   = (float*)alloc(HBYTES);
  float* hB   = (float*)alloc(HBYTES);
  int* cnt    = (int*)alloc(NNODES*sizeof(int));
  int* offs   = (int*)alloc((NNODES+1)*sizeof(int));
  int* cursor = (int*)alloc(NNODES*sizeof(int));
  int* srcl   = (int*)alloc(NE*sizeof(int));
  float* aggb = (float*)alloc(NB*64*sizeof(float));

  // CSR build
  hipMemsetAsync(cnt, 0, NNODES*sizeof(int), stream);
  k_count<<<(NNODES*ND+255)/256, 256, 0, stream>>>(nbr, cnt);
  k_scan<<<1, 1024, 0, stream>>>(cnt, offs, cursor);
  k_fill<<<(NE+255)/256, 256, 0, stream>>>(nbr, cursor, srcl);

  const int NBLK = NNODES*NB/256;     // 2048

  k_t0<<<NBLK, 256, 0, stream>>>(x, hA);
  k_layer<false><<<NBLK, 256, 0, stream>>>(hA, Wl,       Wr,       att,      bias,      offs, srcl, hB);
  k_layer<false><<<NBLK, 256, 0, stream>>>(hB, Wl + 256, Wr + 256, att + 16, bias + 16, offs, srcl, hA);
  k_layer<false><<<NBLK, 256, 0, stream>>>(hA, Wl + 512, Wr + 512, att + 32, bias + 32, offs, srcl, hB);
  k_layer<true ><<<NBLK, 256, 0, stream>>>(hB, Wl + 768, Wr + 768, att + 48, bias + 48, offs, srcl, hA);

  k_agg<<<NB, 1024, 0, stream>>>(hA, Wg1, bg1, Wg2, bg2, aggb);
  k_final<<<NB, 256, 0, stream>>>(hA, agent, nbr, aggb,
                                  We1, be1, We2, be2, We3, be3, out);
}

// Round 3
// 536.694 us; speedup vs baseline: 1.9165x; 1.9165x over previous
//
#include <hip/hip_runtime.h>
#include <cmath>

#define NNODES 8192
#define NB 64
#define ND 5
#define NE (NNODES*(ND+1))

// chunk layout: h/xl stored as [chunk=8][node][b_local=8][hc=16] floats.
// One chunk's slice = 4 MB = one XCD's L2. Node row = 128 floats = 512 B.
#define HROW(c,v) ((((size_t)(c)*NNODES + (v))) << 7)

// ---------------- CSR build (reverse graph: in-edges per dst) ----------------

__global__ void k_count(const int* __restrict__ nbr, int* __restrict__ cnt) {
  int i = blockIdx.x*blockDim.x + threadIdx.x;
  if (i < NNODES*ND) atomicAdd(&cnt[nbr[i]], 1);
}

__global__ void __launch_bounds__(1024)
k_scan(const int* __restrict__ cnt, int* __restrict__ offs, int* __restrict__ cursor) {
  __shared__ int part[1024];
  int t = threadIdx.x;
  const int chunk = NNODES/1024;   // 8
  int base = t*chunk;
  int s = 0;
  for (int i = 0; i < chunk; ++i) s += cnt[base+i] + 1;  // +1 self-loop
  part[t] = s;
  __syncthreads();
  for (int off = 1; off < 1024; off <<= 1) {
    int v = (t >= off) ? part[t-off] : 0;
    __syncthreads();
    part[t] += v;
    __syncthreads();
  }
  int run = (t == 0) ? 0 : part[t-1];
  for (int i = 0; i < chunk; ++i) {
    offs[base+i] = run;
    cursor[base+i] = run;
    run += cnt[base+i] + 1;
  }
  if (t == 1023) offs[NNODES] = run;
}

__global__ void k_fill(const int* __restrict__ nbr, int* __restrict__ cursor, int* __restrict__ srcl) {
  int i = blockIdx.x*blockDim.x + threadIdx.x;
  if (i >= NE) return;
  int u, v;
  if (i < NNODES*ND) { u = i/ND; v = nbr[i]; }
  else               { u = i - NNODES*ND; v = u; }
  int pos = atomicAdd(&cursor[v], 1);
  srcl[pos] = u;
}

// ---------------- t0: x (B,N,16) -> h chunk layout + xl0 = x @ Wl0 ----------------

__global__ void __launch_bounds__(256)
k_t0(const float* __restrict__ x, const float* __restrict__ Wl0,
     float* __restrict__ h, float* __restrict__ xl0) {
  int gid = blockIdx.x*blockDim.x + threadIdx.x;
  int c  = gid >> 16;
  int r  = gid & 65535;
  int v  = r >> 3;
  int bl = r & 7;
  int b  = c*8 + bl;
  const float4* src = (const float4*)(x + (((size_t)b*NNODES + v) << 4));
  float hv[16];
  #pragma unroll
  for (int q = 0; q < 4; ++q) *(float4*)(hv+4*q) = src[q];
  float y[16];
  #pragma unroll
  for (int j = 0; j < 16; ++j) y[j] = 0.f;
  #pragma unroll
  for (int f = 0; f < 16; ++f) {
    float hf = hv[f];
    #pragma unroll
    for (int j = 0; j < 16; ++j) y[j] = fmaf(hf, Wl0[f*16+j], y[j]);
  }
  float* hd = h   + HROW(c,v) + bl*16;
  float* xd = xl0 + HROW(c,v) + bl*16;
  #pragma unroll
  for (int q = 0; q < 4; ++q) { ((float4*)hd)[q] = *(float4*)(hv+4*q); ((float4*)xd)[q] = *(float4*)(y+4*q); }
}

// ---------------- fused GATv2 layer ----------------
// block = 256 thr = 4 waves = 4 dst nodes of chunk c = blockIdx&7 (XCD-pinned).
// lane = bl*8 + pr: handles (b_local=bl, hc={2pr,2pr+1}). Gather = 512B/wave, contiguous.
// Updates h in place; epilogue computes next layer's xl via LDS round-trip.

template<bool LAST>
__global__ void __launch_bounds__(256)
k_layer(float* __restrict__ h, const float* __restrict__ xlin, float* __restrict__ xlout,
        const float* __restrict__ Wr, const float* __restrict__ WlNext,
        const float* __restrict__ att, const float* __restrict__ bias,
        const int* __restrict__ offs, const int* __restrict__ srcl) {
  __shared__ float sm[4][128];
  int c = blockIdx.x & 7;
  int v = ((blockIdx.x >> 3) << 2) + (threadIdx.x >> 6);
  int w = threadIdx.x >> 6;
  int lane = threadIdx.x & 63;
  int bl = lane >> 3, pr = lane & 7;
  int hc0 = pr*2;

  float* hrow = h + HROW(c,v);
  float hv[16];
  const float4* hp = (const float4*)(hrow + bl*16);
  #pragma unroll
  for (int q = 0; q < 4; ++q) *(float4*)(hv+4*q) = hp[q];
  float xr0 = 0.f, xr1 = 0.f;
  #pragma unroll
  for (int f = 0; f < 16; ++f) {
    xr0 = fmaf(hv[f], Wr[f*16+hc0],   xr0);
    xr1 = fmaf(hv[f], Wr[f*16+hc0+1], xr1);
  }
  float a0 = att[hc0], a1 = att[hc0+1];

  float s = 0.f, acc0 = 0.f, acc1 = 0.f;
  int e0 = offs[v], e1 = offs[v+1];
  int u = srcl[e0];
  float2 cur = ((const float2*)(xlin + HROW(c,u)))[lane];
  for (int e = e0; e < e1; ++e) {
    float2 nxt = cur;
    if (e+1 < e1) {
      int u2 = srcl[e+1];
      nxt = ((const float2*)(xlin + HROW(c,u2)))[lane];   // prefetch next edge
    }
    float z0 = cur.x + xr0; z0 = (z0 >= 0.f) ? z0 : 0.2f*z0;
    float z1 = cur.y + xr1; z1 = (z1 >= 0.f) ? z1 : 0.2f*z1;
    float lg = fmaf(z0, a0, z1*a1);
    lg += __shfl_xor(lg, 1);          // combine the head's other c-pair
    float p = __expf(lg);             // no max-rescale: logits bounded, matches R1/R2
    s += p;
    acc0 = fmaf(p, cur.x, acc0);
    acc1 = fmaf(p, cur.y, acc1);
    cur = nxt;
  }

  float inv = 1.f / s;
  float o0 = fmaf(acc0, inv, bias[hc0]);
  float o1 = fmaf(acc1, inv, bias[hc0+1]);
  ((float2*)hrow)[lane] = make_float2(o0, o1);   // in-place: only own row touched

  if (!LAST) {
    sm[w][2*lane]   = o0;
    sm[w][2*lane+1] = o1;
    __syncthreads();
    float hn[16];
    #pragma unroll
    for (int q = 0; q < 4; ++q) *(float4*)(hn+4*q) = *(float4*)&sm[w][bl*16+4*q];
    float y0 = 0.f, y1 = 0.f;
    #pragma unroll
    for (int f = 0; f < 16; ++f) {
      y0 = fmaf(hn[f], WlNext[f*16+hc0],   y0);
      y1 = fmaf(hn[f], WlNext[f*16+hc0+1], y1);
    }
    ((float2*)(xlout + HROW(c,v)))[lane] = make_float2(y0, y1);
  }
}

// ---------------- mean over nodes (partial) + MLP ----------------

__global__ void __launch_bounds__(1024)
k_mean(const float* __restrict__ h, float* __restrict__ meanbuf) {
  int b = blockIdx.x >> 2, q = blockIdx.x & 3;
  int t = threadIdx.x;
  int hc = t & 15, ch = t >> 4;        // 64 chunks of 32 nodes each (per quarter)
  int c = b >> 3, bl = b & 7;
  float s = 0.f;
  int n0 = q*2048 + ch*32;
  for (int i = 0; i < 32; ++i) s += h[HROW(c, n0+i) + bl*16 + hc];
  __shared__ float red[1024];
  red[t] = s;
  __syncthreads();
  for (int off = 512; off >= 16; off >>= 1) {
    if (t < off) red[t] += red[t+off];
    __syncthreads();
  }
  if (t < 16) atomicAdd(&meanbuf[b*16+t], red[t]);
}

__global__ void __launch_bounds__(64)
k_mlp(const float* __restrict__ meanbuf,
      const float* __restrict__ Wg1, const float* __restrict__ bg1,
      const float* __restrict__ Wg2, const float* __restrict__ bg2,
      float* __restrict__ agg) {
  int b = blockIdx.x;
  int t = threadIdx.x;                 // 64
  __shared__ float mean[16], g1[32];
  if (t < 16) mean[t] = meanbuf[b*16+t] * (1.0f/NNODES);
  __syncthreads();
  if (t < 32) {
    float a = bg1[t];
    for (int f = 0; f < 16; ++f) a = fmaf(mean[f], Wg1[f*32+t], a);
    g1[t] = tanhf(a);
  }
  __syncthreads();
  float a = bg2[t];
  for (int f = 0; f < 32; ++f) a = fmaf(g1[f], Wg2[f*64+t], a);
  agg[b*64+t] = tanhf(a);
}

// ---------------- final edge-scoring MLP: feats(99) -> 16 -> 8 -> 1 ----------------

__global__ void k_final(const float* __restrict__ h, const int* __restrict__ agent,
                        const int* __restrict__ nbr, const float* __restrict__ agg,
                        const float* __restrict__ We1, const float* __restrict__ be1,
                        const float* __restrict__ We2, const float* __restrict__ be2,
                        const float* __restrict__ We3, const float* __restrict__ be3,
                        float* __restrict__ out) {
  int b = blockIdx.x;
  int t = threadIdx.x;                 // 256
  int c = b >> 3, bl = b & 7;
  __shared__ float srcv[16];
  __shared__ float tgt[5][16];
  __shared__ float aggs[64];
  __shared__ float e1s[15][16];
  __shared__ float e2s[15][8];
  int an = agent[b];
  if (t < 16) srcv[t] = h[HROW(c,an) + bl*16 + t];
  if (t >= 32 && t < 112) {
    int d = (t-32)/16, k = (t-32)%16;
    int nn = nbr[an*ND + d];
    tgt[d][k] = h[HROW(c,nn) + bl*16 + k];
  }
  if (t >= 128 && t < 192) aggs[t-128] = agg[b*64 + (t-128)];
  __syncthreads();
  if (t < 240) {
    int j = t & 15, td = t >> 4;       // td = tk*5+d
    int tk = td/5, d = td%5;
    float a = be1[j];
    for (int k = 0; k < 16; ++k) a = fmaf(srcv[k],  We1[k*16+j],      a);
    a += We1[(16+tk)*16 + j];          // one-hot token rows 16..18
    for (int k = 0; k < 16; ++k) a = fmaf(tgt[d][k], We1[(19+k)*16+j], a);
    for (int k = 0; k < 64; ++k) a = fmaf(aggs[k],  We1[(35+k)*16+j], a);
    e1s[td][j] = tanhf(a);
  }
  __syncthreads();
  if (t < 120) {
    int j = t & 7, td = t >> 3;
    float a = be2[j];
    for (int k = 0; k < 16; ++k) a = fmaf(e1s[td][k], We2[k*8+j], a);
    e2s[td][j] = tanhf(a);
  }
  __syncthreads();
  if (t < 15) {
    float a = be3[0];
    for (int k = 0; k < 8; ++k) a = fmaf(e2s[t][k], We3[k], a);
    out[b*15 + t] = a;
  }
}

// ---------------- launch ----------------

extern "C" void kernel_launch(void* const* d_in, const int* in_sizes, int n_in,
                              void* d_out, int out_size, void* d_ws, size_t ws_size,
                              hipStream_t stream) {
  const float* x     = (const float*)d_in[0];
  const int*   agent = (const int*)  d_in[1];
  const int*   nbr   = (const int*)  d_in[2];
  const float* Wl    = (const float*)d_in[3];   // (4,16,4,4)
  const float* Wr    = (const float*)d_in[4];
  const float* att   = (const float*)d_in[5];   // (4,4,4)
  const float* bias  = (const float*)d_in[6];   // (4,16)
  const float* Wg1   = (const float*)d_in[7];
  const float* bg1   = (const float*)d_in[8];
  const float* Wg2   = (const float*)d_in[9];
  const float* bg2   = (const float*)d_in[10];
  const float* We1   = (const float*)d_in[11];
  const float* be1   = (const float*)d_in[12];
  const float* We2   = (const float*)d_in[13];
  const float* be2   = (const float*)d_in[14];
  const float* We3   = (const float*)d_in[15];
  const float* be3   = (const float*)d_in[16];
  float* out = (float*)d_out;

  char* ws = (char*)d_ws;
  size_t off = 0;
  auto alloc = [&](size_t bytes) -> void* {
    void* p = ws + off;
    off += (bytes + 255) & ~(size_t)255;
    return p;
  };
  const size_t HBYTES = (size_t)NNODES*128*8*sizeof(float);   // 32 MB
  float* h    = (float*)alloc(HBYTES);
  float* xlA  = (float*)alloc(HBYTES);
  float* xlB  = (float*)alloc(HBYTES);
  int* cnt    = (int*)alloc(NNODES*sizeof(int));
  int* offs   = (int*)alloc((NNODES+1)*sizeof(int));
  int* cursor = (int*)alloc(NNODES*sizeof(int));
  int* srcl   = (int*)alloc(NE*sizeof(int));
  float* meanbuf = (float*)alloc(NB*16*sizeof(float));
  float* aggb    = (float*)alloc(NB*64*sizeof(float));

  // CSR build
  hipMemsetAsync(cnt, 0, NNODES*sizeof(int), stream);
  hipMemsetAsync(meanbuf, 0, NB*16*sizeof(float), stream);
  k_count<<<(NNODES*ND+255)/256, 256, 0, stream>>>(nbr, cnt);
  k_scan<<<1, 1024, 0, stream>>>(cnt, offs, cursor);
  k_fill<<<(NE+255)/256, 256, 0, stream>>>(nbr, cursor, srcl);

  k_t0<<<NNODES*NB/256, 256, 0, stream>>>(x, Wl, h, xlA);

  const int NBLK = (NNODES/4)*8;      // 16384 blocks, chunk = blockIdx&7
  k_layer<false><<<NBLK, 256, 0, stream>>>(h, xlA, xlB, Wr,       Wl + 256, att,      bias,      offs, srcl);
  k_layer<false><<<NBLK, 256, 0, stream>>>(h, xlB, xlA, Wr + 256, Wl + 512, att + 16, bias + 16, offs, srcl);
  k_layer<false><<<NBLK, 256, 0, stream>>>(h, xlA, xlB, Wr + 512, Wl + 768, att + 32, bias + 32, offs, srcl);
  k_layer<true ><<<NBLK, 256, 0, stream>>>(h, xlB, xlA, Wr + 768, nullptr,  att + 48, bias + 48, offs, srcl);

  k_mean<<<NB*4, 1024, 0, stream>>>(h, meanbuf);
  k_mlp<<<NB, 64, 0, stream>>>(meanbuf, Wg1, bg1, Wg2, bg2, aggb);
  k_final<<<NB, 256, 0, stream>>>(h, agent, nbr, aggb,
                                  We1, be1, We2, be2, We3, be3, out);
}

// Round 4
// 351.232 us; speedup vs baseline: 2.9285x; 1.5280x over previous
//
#include <hip/hip_runtime.h>
#include <cmath>

#define NNODES 8192
#define NB 64
#define ND 5
#define NE (NNODES*(ND+1))

// h / xl layout: [node][b=64][hc=16] floats. One node row = 4 KB, so a
// wave (lane=b) gathers a node row as 4 contiguous float4 loads = 4 KB/wave.

// ---------------- CSR build (reverse graph: in-edges per dst) ----------------

__global__ void k_count(const int* __restrict__ nbr, int* __restrict__ cnt) {
  int i = blockIdx.x*blockDim.x + threadIdx.x;
  if (i < NNODES*ND) atomicAdd(&cnt[nbr[i]], 1);
}

__global__ void __launch_bounds__(1024)
k_scan(const int* __restrict__ cnt, int* __restrict__ offs, int* __restrict__ cursor) {
  __shared__ int part[1024];
  int t = threadIdx.x;
  const int chunk = NNODES/1024;   // 8
  int base = t*chunk;
  int s = 0;
  for (int i = 0; i < chunk; ++i) s += cnt[base+i] + 1;  // +1 self-loop
  part[t] = s;
  __syncthreads();
  for (int off = 1; off < 1024; off <<= 1) {
    int v = (t >= off) ? part[t-off] : 0;
    __syncthreads();
    part[t] += v;
    __syncthreads();
  }
  int run = (t == 0) ? 0 : part[t-1];
  for (int i = 0; i < chunk; ++i) {
    offs[base+i] = run;
    cursor[base+i] = run;
    run += cnt[base+i] + 1;
  }
  if (t == 1023) offs[NNODES] = run;
}

__global__ void k_fill(const int* __restrict__ nbr, int* __restrict__ cursor, int* __restrict__ srcl) {
  int i = blockIdx.x*blockDim.x + threadIdx.x;
  if (i >= NE) return;
  int u, v;
  if (i < NNODES*ND) { u = i/ND; v = nbr[i]; }
  else               { u = i - NNODES*ND; v = u; }
  int pos = atomicAdd(&cursor[v], 1);
  srcl[pos] = u;
}

// ---------------- t0: x (B,N,16) -> h [N][64][16]  +  xl0 = x @ Wl0 ----------------

__global__ void __launch_bounds__(256)
k_t0(const float* __restrict__ x, const float* __restrict__ Wl0,
     float* __restrict__ h, float* __restrict__ xl0) {
  int gid = blockIdx.x*blockDim.x + threadIdx.x;
  int n = gid >> 6;
  int b = gid & 63;
  const float4* src = (const float4*)(x + (((size_t)b*NNODES + n) << 4));
  float hv[16];
  #pragma unroll
  for (int q = 0; q < 4; ++q) *(float4*)(hv+4*q) = src[q];
  float y[16];
  #pragma unroll
  for (int j = 0; j < 16; ++j) y[j] = 0.f;
  #pragma unroll
  for (int f = 0; f < 16; ++f) {
    float hf = hv[f];
    #pragma unroll
    for (int j = 0; j < 16; ++j) y[j] = fmaf(hf, Wl0[f*16+j], y[j]);
  }
  size_t boff = ((size_t)n << 10) + (b << 4);
  #pragma unroll
  for (int q = 0; q < 4; ++q) {
    ((float4*)(h   + boff))[q] = *(float4*)(hv+4*q);
    ((float4*)(xl0 + boff))[q] = *(float4*)(y +4*q);
  }
}

// ---------------- fused GATv2 layer ----------------
// wave = dst node v, lane = batch b. Gathers xl[u] rows (4 KB/wave, contiguous),
// depth-2 software pipeline (tA/tB) for ~8 outstanding float4 loads per wave.
// Epilogue: writes h in place (own row only) and next layer's xl = o @ WlNext.

template<bool LAST>
__global__ void __launch_bounds__(256)
k_layer(float* __restrict__ h, const float* __restrict__ xlin, float* __restrict__ xlout,
        const float* __restrict__ Wr, const float* __restrict__ WlNext,
        const float* __restrict__ att, const float* __restrict__ bias,
        const int* __restrict__ offs, const int* __restrict__ srcl) {
  int gid = blockIdx.x*blockDim.x + threadIdx.x;
  int v = gid >> 6;
  int b = gid & 63;
  size_t boff = (size_t)(b << 4);

  // own row -> xr = Wr^T h[v]
  const float4* hp = (const float4*)(h + ((size_t)v << 10) + boff);
  float hv[16];
  #pragma unroll
  for (int q = 0; q < 4; ++q) *(float4*)(hv+4*q) = hp[q];
  float xr[16];
  #pragma unroll
  for (int j = 0; j < 16; ++j) xr[j] = 0.f;
  #pragma unroll
  for (int f = 0; f < 16; ++f) {
    float hf = hv[f];
    #pragma unroll
    for (int j = 0; j < 16; ++j) xr[j] = fmaf(hf, Wr[f*16+j], xr[j]);
  }
  float aw[16];
  #pragma unroll
  for (int j = 0; j < 16; ++j) aw[j] = att[j];

  float s4[4] = {0.f, 0.f, 0.f, 0.f};
  float acc[16];
  #pragma unroll
  for (int j = 0; j < 16; ++j) acc[j] = 0.f;

  int e0 = offs[v], e1 = offs[v+1];

  float tA[16], tB[16];
  {
    int u = srcl[e0];
    const float4* sp = (const float4*)(xlin + ((size_t)u << 10) + boff);
    #pragma unroll
    for (int q = 0; q < 4; ++q) *(float4*)(tA+4*q) = sp[q];
  }
  if (e0+1 < e1) {
    int u = srcl[e0+1];
    const float4* sp = (const float4*)(xlin + ((size_t)u << 10) + boff);
    #pragma unroll
    for (int q = 0; q < 4; ++q) *(float4*)(tB+4*q) = sp[q];
  }

  auto process = [&](const float* t) {
    #pragma unroll
    for (int hh = 0; hh < 4; ++hh) {
      float lg = 0.f;
      #pragma unroll
      for (int c = 0; c < 4; ++c) {
        float z = t[hh*4+c] + xr[hh*4+c];
        z = (z >= 0.f) ? z : 0.2f*z;       // leaky_relu slope 0.2
        lg = fmaf(z, aw[hh*4+c], lg);
      }
      float p = __expf(lg);                // no max-rescale: logits bounded
      s4[hh] += p;
      #pragma unroll
      for (int c = 0; c < 4; ++c) acc[hh*4+c] = fmaf(p, t[hh*4+c], acc[hh*4+c]);
    }
  };

  int e = e0;
  for (; e+1 < e1; e += 2) {
    process(tA);
    if (e+2 < e1) {
      int u = srcl[e+2];
      const float4* sp = (const float4*)(xlin + ((size_t)u << 10) + boff);
      #pragma unroll
      for (int q = 0; q < 4; ++q) *(float4*)(tA+4*q) = sp[q];
    }
    process(tB);
    if (e+3 < e1) {
      int u = srcl[e+3];
      const float4* sp = (const float4*)(xlin + ((size_t)u << 10) + boff);
      #pragma unroll
      for (int q = 0; q < 4; ++q) *(float4*)(tB+4*q) = sp[q];
    }
  }
  if (e < e1) process(tA);   // odd-degree tail

  float o[16];
  #pragma unroll
  for (int hh = 0; hh < 4; ++hh) {
    float inv = 1.f / s4[hh];
    #pragma unroll
    for (int c = 0; c < 4; ++c) o[hh*4+c] = fmaf(acc[hh*4+c], inv, bias[hh*4+c]);
  }
  float4* hd = (float4*)(h + ((size_t)v << 10) + boff);
  #pragma unroll
  for (int q = 0; q < 4; ++q) hd[q] = *(float4*)(o+4*q);   // in place: own row only

  if (!LAST) {
    float y[16];
    #pragma unroll
    for (int j = 0; j < 16; ++j) y[j] = 0.f;
    #pragma unroll
    for (int f = 0; f < 16; ++f) {
      float of = o[f];
      #pragma unroll
      for (int j = 0; j < 16; ++j) y[j] = fmaf(of, WlNext[f*16+j], y[j]);
    }
    float4* xd = (float4*)(xlout + ((size_t)v << 10) + boff);
    #pragma unroll
    for (int q = 0; q < 4; ++q) xd[q] = *(float4*)(y+4*q);
  }
}

// ---------------- mean over nodes (partial, coalesced) ----------------

__global__ void __launch_bounds__(256)
k_mean(const float* __restrict__ h, float* __restrict__ meanbuf) {
  int bk = blockIdx.x;                 // 256 blocks, 32 nodes each
  int t = threadIdx.x;
  int b = t >> 2, q = t & 3;           // thread owns (b, float4 q)
  float4 s = make_float4(0.f, 0.f, 0.f, 0.f);
  int n0 = bk*32;
  for (int i = 0; i < 32; ++i) {
    float4 vv = ((const float4*)(h + (((size_t)(n0+i)) << 10) + (b << 4)))[q];
    s.x += vv.x; s.y += vv.y; s.z += vv.z; s.w += vv.w;
  }
  float* mb = meanbuf + b*16 + q*4;
  atomicAdd(mb+0, s.x); atomicAdd(mb+1, s.y);
  atomicAdd(mb+2, s.z); atomicAdd(mb+3, s.w);
}

__global__ void __launch_bounds__(64)
k_mlp(const float* __restrict__ meanbuf,
      const float* __restrict__ Wg1, const float* __restrict__ bg1,
      const float* __restrict__ Wg2, const float* __restrict__ bg2,
      float* __restrict__ agg) {
  int b = blockIdx.x;
  int t = threadIdx.x;                 // 64
  __shared__ float mean[16], g1[32];
  if (t < 16) mean[t] = meanbuf[b*16+t] * (1.0f/NNODES);
  __syncthreads();
  if (t < 32) {
    float a = bg1[t];
    for (int f = 0; f < 16; ++f) a = fmaf(mean[f], Wg1[f*32+t], a);
    g1[t] = tanhf(a);
  }
  __syncthreads();
  float a = bg2[t];
  for (int f = 0; f < 32; ++f) a = fmaf(g1[f], Wg2[f*64+t], a);
  agg[b*64+t] = tanhf(a);
}

// ---------------- final edge-scoring MLP: feats(99) -> 16 -> 8 -> 1 ----------------

__global__ void k_final(const float* __restrict__ h, const int* __restrict__ agent,
                        const int* __restrict__ nbr, const float* __restrict__ agg,
                        const float* __restrict__ We1, const float* __restrict__ be1,
                        const float* __restrict__ We2, const float* __restrict__ be2,
                        const float* __restrict__ We3, const float* __restrict__ be3,
                        float* __restrict__ out) {
  int b = blockIdx.x;
  int t = threadIdx.x;                 // 256
  __shared__ float srcv[16];
  __shared__ float tgt[5][16];
  __shared__ float aggs[64];
  __shared__ float e1s[15][16];
  __shared__ float e2s[15][8];
  int an = agent[b];
  if (t < 16) srcv[t] = h[((size_t)an << 10) + (b << 4) + t];
  if (t >= 32 && t < 112) {
    int d = (t-32)/16, k = (t-32)%16;
    int nn = nbr[an*ND + d];
    tgt[d][k] = h[((size_t)nn << 10) + (b << 4) + k];
  }
  if (t >= 128 && t < 192) aggs[t-128] = agg[b*64 + (t-128)];
  __syncthreads();
  if (t < 240) {
    int j = t & 15, td = t >> 4;       // td = tk*5+d
    int tk = td/5, d = td%5;
    float a = be1[j];
    for (int k = 0; k < 16; ++k) a = fmaf(srcv[k],  We1[k*16+j],      a);
    a += We1[(16+tk)*16 + j];          // one-hot token rows 16..18
    for (int k = 0; k < 16; ++k) a = fmaf(tgt[d][k], We1[(19+k)*16+j], a);
    for (int k = 0; k < 64; ++k) a = fmaf(aggs[k],  We1[(35+k)*16+j], a);
    e1s[td][j] = tanhf(a);
  }
  __syncthreads();
  if (t < 120) {
    int j = t & 7, td = t >> 3;
    float a = be2[j];
    for (int k = 0; k < 16; ++k) a = fmaf(e1s[td][k], We2[k*8+j], a);
    e2s[td][j] = tanhf(a);
  }
  __syncthreads();
  if (t < 15) {
    float a = be3[0];
    for (int k = 0; k < 8; ++k) a = fmaf(e2s[t][k], We3[k], a);
    out[b*15 + t] = a;
  }
}

// ---------------- launch ----------------

extern "C" void kernel_launch(void* const* d_in, const int* in_sizes, int n_in,
                              void* d_out, int out_size, void* d_ws, size_t ws_size,
                              hipStream_t stream) {
  const float* x     = (const float*)d_in[0];
  const int*   agent = (const int*)  d_in[1];
  const int*   nbr   = (const int*)  d_in[2];
  const float* Wl    = (const float*)d_in[3];   // (4,16,4,4)
  const float* Wr    = (const float*)d_in[4];
  const float* att   = (const float*)d_in[5];   // (4,4,4)
  const float* bias  = (const float*)d_in[6];   // (4,16)
  const float* Wg1   = (const float*)d_in[7];
  const float* bg1   = (const float*)d_in[8];
  const float* Wg2   = (const float*)d_in[9];
  const float* bg2   = (const float*)d_in[10];
  const float* We1   = (const float*)d_in[11];
  const float* be1   = (const float*)d_in[12];
  const float* We2   = (const float*)d_in[13];
  const float* be2   = (const float*)d_in[14];
  const float* We3   = (const float*)d_in[15];
  const float* be3   = (const float*)d_in[16];
  float* out = (float*)d_out;

  char* ws = (char*)d_ws;
  size_t off = 0;
  auto alloc = [&](size_t bytes) -> void* {
    void* p = ws + off;
    off += (bytes + 255) & ~(size_t)255;
    return p;
  };
  const size_t HBYTES = (size_t)NNODES*NB*16*sizeof(float);   // 32 MB
  float* h    = (float*)alloc(HBYTES);
  float* xlA  = (float*)alloc(HBYTES);
  float* xlB  = (float*)alloc(HBYTES);
  int* cnt    = (int*)alloc(NNODES*sizeof(int));
  int* offs   = (int*)alloc((NNODES+1)*sizeof(int));
  int* cursor = (int*)alloc(NNODES*sizeof(int));
  int* srcl   = (int*)alloc(NE*sizeof(int));
  float* meanbuf = (float*)alloc(NB*16*sizeof(float));
  float* aggb    = (float*)alloc(NB*64*sizeof(float));

  // CSR build
  hipMemsetAsync(cnt, 0, NNODES*sizeof(int), stream);
  hipMemsetAsync(meanbuf, 0, NB*16*sizeof(float), stream);
  k_count<<<(NNODES*ND+255)/256, 256, 0, stream>>>(nbr, cnt);
  k_scan<<<1, 1024, 0, stream>>>(cnt, offs, cursor);
  k_fill<<<(NE+255)/256, 256, 0, stream>>>(nbr, cursor, srcl);

  const int NBLK = NNODES*NB/256;     // 2048 blocks, wave = one node

  k_t0<<<NBLK, 256, 0, stream>>>(x, Wl, h, xlA);
  k_layer<false><<<NBLK, 256, 0, stream>>>(h, xlA, xlB, Wr,       Wl + 256, att,      bias,      offs, srcl);
  k_layer<false><<<NBLK, 256, 0, stream>>>(h, xlB, xlA, Wr + 256, Wl + 512, att + 16, bias + 16, offs, srcl);
  k_layer<false><<<NBLK, 256, 0, stream>>>(h, xlA, xlB, Wr + 512, Wl + 768, att + 32, bias + 32, offs, srcl);
  k_layer<true ><<<NBLK, 256, 0, stream>>>(h, xlB, nullptr, Wr + 768, nullptr, att + 48, bias + 48, offs, srcl);

  k_mean<<<256, 256, 0, stream>>>(h, meanbuf);
  k_mlp<<<NB, 64, 0, stream>>>(meanbuf, Wg1, bg1, Wg2, bg2, aggb);
  k_final<<<NB, 256, 0, stream>>>(h, agent, nbr, aggb,
                                  We1, be1, We2, be2, We3, be3, out);
}

// Round 5
// 282.348 us; speedup vs baseline: 3.6429x; 1.2440x over previous
//
#include <hip/hip_runtime.h>
#include <hip/hip_fp16.h>
#include <cmath>

#define NNODES 8192
#define NB 64
#define ND 5
#define MAXDEG 64

// h layout: [node][b=64][hc=16] fp32 (4 KB/row).  xl layout: same order, fp16 (2 KB/row).
// Wave = one node, lane = batch b: every gather is a contiguous 2 KB wave read.

// ---------------- slot-table build (replaces count/scan/fill CSR) ----------------

__global__ void k_fill0(int* __restrict__ cnt, int* __restrict__ slot, float* __restrict__ meanbuf) {
  int v = blockIdx.x*blockDim.x + threadIdx.x;   // 8192
  cnt[v] = 1;                                    // self-loop pre-seeded
  slot[v*MAXDEG] = v;
  if (v < NB*16) meanbuf[v] = 0.f;
}

__global__ void k_fill(const int* __restrict__ nbr, int* __restrict__ cnt, int* __restrict__ slot) {
  int i = blockIdx.x*blockDim.x + threadIdx.x;   // 40960 edges
  int v = nbr[i];
  int pos = atomicAdd(&cnt[v], 1);
  slot[v*MAXDEG + pos] = i/ND;                   // src node u
}

// ---------------- t0: x (B,N,16) -> h [N][64][16] fp32 + xl0 = x @ Wl0 (fp16) ----------------

__global__ void __launch_bounds__(256)
k_t0(const float* __restrict__ x, const float* __restrict__ Wl0,
     float* __restrict__ h, __half* __restrict__ xl0) {
  int gid = blockIdx.x*blockDim.x + threadIdx.x;
  int n = gid >> 6;
  int b = gid & 63;
  const float4* src = (const float4*)(x + (((size_t)b*NNODES + n) << 4));
  float hv[16];
  #pragma unroll
  for (int q = 0; q < 4; ++q) *(float4*)(hv+4*q) = src[q];
  float y[16];
  #pragma unroll
  for (int j = 0; j < 16; ++j) y[j] = 0.f;
  #pragma unroll
  for (int f = 0; f < 16; ++f) {
    float hf = hv[f];
    #pragma unroll
    for (int j = 0; j < 16; ++j) y[j] = fmaf(hf, Wl0[f*16+j], y[j]);
  }
  size_t idx = ((size_t)n << 10) + (b << 4);
  #pragma unroll
  for (int q = 0; q < 4; ++q) ((float4*)(h + idx))[q] = *(float4*)(hv+4*q);
  __half2 yh[8];
  #pragma unroll
  for (int j = 0; j < 8; ++j) yh[j] = __floats2half2_rn(y[2*j], y[2*j+1]);
  float4* xd = (float4*)(xl0 + idx);
  xd[0] = *(float4*)&yh[0];
  xd[1] = *(float4*)&yh[4];
}

// ---------------- fused GATv2 layer ----------------
// wave = dst node v, lane = batch b. Gathers fp16 xl[u] rows (2 KB/wave),
// depth-2 pipeline. Epilogue: h in place + next layer's xl (fp16) = o @ WlNext.

__device__ inline void cvt16(const float4& r0, const float4& r1, float* t) {
  const __half2* a = (const __half2*)&r0;
  const __half2* b = (const __half2*)&r1;
  #pragma unroll
  for (int q = 0; q < 4; ++q) { float2 f = __half22float2(a[q]); t[2*q]   = f.x; t[2*q+1]   = f.y; }
  #pragma unroll
  for (int q = 0; q < 4; ++q) { float2 f = __half22float2(b[q]); t[8+2*q] = f.x; t[8+2*q+1] = f.y; }
}

template<bool LAST>
__global__ void __launch_bounds__(256)
k_layer(float* __restrict__ h, const __half* __restrict__ xlin, __half* __restrict__ xlout,
        const float* __restrict__ Wr, const float* __restrict__ WlNext,
        const float* __restrict__ att, const float* __restrict__ bias,
        const int* __restrict__ cnt, const int* __restrict__ slot) {
  int gid = blockIdx.x*blockDim.x + threadIdx.x;
  int v = gid >> 6;
  int b = gid & 63;
  size_t boff = (size_t)(b << 4);

  // own row -> xr = Wr^T h[v]
  const float4* hp = (const float4*)(h + ((size_t)v << 10) + boff);
  float hv[16];
  #pragma unroll
  for (int q = 0; q < 4; ++q) *(float4*)(hv+4*q) = hp[q];
  float xr[16];
  #pragma unroll
  for (int j = 0; j < 16; ++j) xr[j] = 0.f;
  #pragma unroll
  for (int f = 0; f < 16; ++f) {
    float hf = hv[f];
    #pragma unroll
    for (int j = 0; j < 16; ++j) xr[j] = fmaf(hf, Wr[f*16+j], xr[j]);
  }
  float aw[16];
  #pragma unroll
  for (int j = 0; j < 16; ++j) aw[j] = att[j];

  float s4[4] = {0.f, 0.f, 0.f, 0.f};
  float acc[16];
  #pragma unroll
  for (int j = 0; j < 16; ++j) acc[j] = 0.f;

  int deg = cnt[v];
  const int* sl = slot + v*MAXDEG;

  float4 rA0, rA1, rB0, rB1;
  {
    int u = sl[0];
    const float4* sp = (const float4*)(xlin + ((size_t)u << 10) + boff);
    rA0 = sp[0]; rA1 = sp[1];
  }
  if (1 < deg) {
    int u = sl[1];
    const float4* sp = (const float4*)(xlin + ((size_t)u << 10) + boff);
    rB0 = sp[0]; rB1 = sp[1];
  }

  auto process = [&](const float4& r0, const float4& r1) {
    float t[16];
    cvt16(r0, r1, t);
    #pragma unroll
    for (int hh = 0; hh < 4; ++hh) {
      float lg = 0.f;
      #pragma unroll
      for (int c = 0; c < 4; ++c) {
        float z = t[hh*4+c] + xr[hh*4+c];
        z = (z >= 0.f) ? z : 0.2f*z;       // leaky_relu slope 0.2
        lg = fmaf(z, aw[hh*4+c], lg);
      }
      float p = __expf(lg);                // no max-rescale: logits bounded
      s4[hh] += p;
      #pragma unroll
      for (int c = 0; c < 4; ++c) acc[hh*4+c] = fmaf(p, t[hh*4+c], acc[hh*4+c]);
    }
  };

  int e = 0;
  for (; e+1 < deg; e += 2) {
    float4 c0 = rA0, c1 = rA1;
    if (e+2 < deg) {
      int u = sl[e+2];
      const float4* sp = (const float4*)(xlin + ((size_t)u << 10) + boff);
      rA0 = sp[0]; rA1 = sp[1];
    }
    process(c0, c1);
    float4 d0 = rB0, d1 = rB1;
    if (e+3 < deg) {
      int u = sl[e+3];
      const float4* sp = (const float4*)(xlin + ((size_t)u << 10) + boff);
      rB0 = sp[0]; rB1 = sp[1];
    }
    process(d0, d1);
  }
  if (e < deg) process(rA0, rA1);          // odd-degree tail

  float o[16];
  #pragma unroll
  for (int hh = 0; hh < 4; ++hh) {
    float inv = 1.f / s4[hh];
    #pragma unroll
    for (int c = 0; c < 4; ++c) o[hh*4+c] = fmaf(acc[hh*4+c], inv, bias[hh*4+c]);
  }
  float4* hd = (float4*)(h + ((size_t)v << 10) + boff);
  #pragma unroll
  for (int q = 0; q < 4; ++q) hd[q] = *(float4*)(o+4*q);   // in place: own row only

  if (!LAST) {
    float y[16];
    #pragma unroll
    for (int j = 0; j < 16; ++j) y[j] = 0.f;
    #pragma unroll
    for (int f = 0; f < 16; ++f) {
      float of = o[f];
      #pragma unroll
      for (int j = 0; j < 16; ++j) y[j] = fmaf(of, WlNext[f*16+j], y[j]);
    }
    __half2 yh[8];
    #pragma unroll
    for (int j = 0; j < 8; ++j) yh[j] = __floats2half2_rn(y[2*j], y[2*j+1]);
    float4* xd = (float4*)(xlout + ((size_t)v << 10) + boff);
    xd[0] = *(float4*)&yh[0];
    xd[1] = *(float4*)&yh[4];
  }
}

// ---------------- mean over nodes (partial, coalesced, atomics) ----------------

__global__ void __launch_bounds__(256)
k_mean(const float* __restrict__ h, float* __restrict__ meanbuf) {
  int bk = blockIdx.x;                 // 256 blocks, 32 nodes each
  int t = threadIdx.x;
  int b = t >> 2, q = t & 3;           // thread owns (b, float4 q)
  float4 s = make_float4(0.f, 0.f, 0.f, 0.f);
  int n0 = bk*32;
  for (int i = 0; i < 32; ++i) {
    float4 vv = ((const float4*)(h + (((size_t)(n0+i)) << 10) + (b << 4)))[q];
    s.x += vv.x; s.y += vv.y; s.z += vv.z; s.w += vv.w;
  }
  float* mb = meanbuf + b*16 + q*4;
  atomicAdd(mb+0, s.x); atomicAdd(mb+1, s.y);
  atomicAdd(mb+2, s.z); atomicAdd(mb+3, s.w);
}

// ---------------- fused tail: mean MLP + edge-scoring MLP (one block per b) ----------------

__global__ void __launch_bounds__(256)
k_tail(const float* __restrict__ h, const int* __restrict__ agent,
       const int* __restrict__ nbr, const float* __restrict__ meanbuf,
       const float* __restrict__ Wg1, const float* __restrict__ bg1,
       const float* __restrict__ Wg2, const float* __restrict__ bg2,
       const float* __restrict__ We1, const float* __restrict__ be1,
       const float* __restrict__ We2, const float* __restrict__ be2,
       const float* __restrict__ We3, const float* __restrict__ be3,
       float* __restrict__ out) {
  int b = blockIdx.x;
  int t = threadIdx.x;                 // 256
  __shared__ float mean[16], g1[32], aggs[64];
  __shared__ float srcv[16];
  __shared__ float tgt[5][16];
  __shared__ float e1s[15][16];
  __shared__ float e2s[15][8];
  int an = agent[b];
  if (t < 16) mean[t] = meanbuf[b*16+t] * (1.0f/NNODES);
  if (t >= 64 && t < 80) srcv[t-64] = h[((size_t)an << 10) + (b << 4) + (t-64)];
  if (t >= 96 && t < 176) {
    int d = (t-96)/16, k = (t-96)%16;
    int nn = nbr[an*ND + d];
    tgt[d][k] = h[((size_t)nn << 10) + (b << 4) + k];
  }
  __syncthreads();
  if (t < 32) {
    float a = bg1[t];
    for (int f = 0; f < 16; ++f) a = fmaf(mean[f], Wg1[f*32+t], a);
    g1[t] = tanhf(a);
  }
  __syncthreads();
  if (t < 64) {
    float a = bg2[t];
    for (int f = 0; f < 32; ++f) a = fmaf(g1[f], Wg2[f*64+t], a);
    aggs[t] = tanhf(a);
  }
  __syncthreads();
  if (t < 240) {
    int j = t & 15, td = t >> 4;       // td = tk*5+d
    int tk = td/5, d = td%5;
    float a = be1[j];
    for (int k = 0; k < 16; ++k) a = fmaf(srcv[k],  We1[k*16+j],      a);
    a += We1[(16+tk)*16 + j];          // one-hot token rows 16..18
    for (int k = 0; k < 16; ++k) a = fmaf(tgt[d][k], We1[(19+k)*16+j], a);
    for (int k = 0; k < 64; ++k) a = fmaf(aggs[k],  We1[(35+k)*16+j], a);
    e1s[td][j] = tanhf(a);
  }
  __syncthreads();
  if (t < 120) {
    int j = t & 7, td = t >> 3;
    float a = be2[j];
    for (int k = 0; k < 16; ++k) a = fmaf(e1s[td][k], We2[k*8+j], a);
    e2s[td][j] = tanhf(a);
  }
  __syncthreads();
  if (t < 15) {
    float a = be3[0];
    for (int k = 0; k < 8; ++k) a = fmaf(e2s[t][k], We3[k], a);
    out[b*15 + t] = a;
  }
}

// ---------------- launch ----------------

extern "C" void kernel_launch(void* const* d_in, const int* in_sizes, int n_in,
                              void* d_out, int out_size, void* d_ws, size_t ws_size,
                              hipStream_t stream) {
  const float* x     = (const float*)d_in[0];
  const int*   agent = (const int*)  d_in[1];
  const int*   nbr   = (const int*)  d_in[2];
  const float* Wl    = (const float*)d_in[3];   // (4,16,4,4)
  const float* Wr    = (const float*)d_in[4];
  const float* att   = (const float*)d_in[5];   // (4,4,4)
  const float* bias  = (const float*)d_in[6];   // (4,16)
  const float* Wg1   = (const float*)d_in[7];
  const float* bg1   = (const float*)d_in[8];
  const float* Wg2   = (const float*)d_in[9];
  const float* bg2   = (const float*)d_in[10];
  const float* We1   = (const float*)d_in[11];
  const float* be1   = (const float*)d_in[12];
  const float* We2   = (const float*)d_in[13];
  const float* be2   = (const float*)d_in[14];
  const float* We3   = (const float*)d_in[15];
  const float* be3   = (const float*)d_in[16];
  float* out = (float*)d_out;

  char* ws = (char*)d_ws;
  size_t off = 0;
  auto alloc = [&](size_t bytes) -> void* {
    void* p = ws + off;
    off += (bytes + 255) & ~(size_t)255;
    return p;
  };
  const size_t HBYTES  = (size_t)NNODES*NB*16*sizeof(float);    // 32 MB
  const size_t XLBYTES = (size_t)NNODES*NB*16*sizeof(__half);   // 16 MB
  float*  h    = (float*)alloc(HBYTES);
  __half* xlA  = (__half*)alloc(XLBYTES);
  __half* xlB  = (__half*)alloc(XLBYTES);
  int* cnt     = (int*)alloc(NNODES*sizeof(int));
  int* slot    = (int*)alloc((size_t)NNODES*MAXDEG*sizeof(int));
  float* meanbuf = (float*)alloc(NB*16*sizeof(float));

  k_fill0<<<NNODES/256, 256, 0, stream>>>(cnt, slot, meanbuf);
  k_fill<<<NNODES*ND/256, 256, 0, stream>>>(nbr, cnt, slot);

  const int NBLK = NNODES*NB/256;     // 2048 blocks, wave = one node

  k_t0<<<NBLK, 256, 0, stream>>>(x, Wl, h, xlA);
  k_layer<false><<<NBLK, 256, 0, stream>>>(h, xlA, xlB, Wr,       Wl + 256, att,      bias,      cnt, slot);
  k_layer<false><<<NBLK, 256, 0, stream>>>(h, xlB, xlA, Wr + 256, Wl + 512, att + 16, bias + 16, cnt, slot);
  k_layer<false><<<NBLK, 256, 0, stream>>>(h, xlA, xlB, Wr + 512, Wl + 768, att + 32, bias + 32, cnt, slot);
  k_layer<true ><<<NBLK, 256, 0, stream>>>(h, xlB, nullptr, Wr + 768, nullptr, att + 48, bias + 48, cnt, slot);

  k_mean<<<256, 256, 0, stream>>>(h, meanbuf);
  k_tail<<<NB, 256, 0, stream>>>(h, agent, nbr, meanbuf,
                                 Wg1, bg1, Wg2, bg2,
                                 We1, be1, We2, be2, We3, be3, out);
}

// Round 7
// 254.103 us; speedup vs baseline: 4.0479x; 1.1112x over previous
//
#include <hip/hip_runtime.h>
#include <hip/hip_fp16.h>
#include <cmath>

#define NNODES 8192
#define NB 64
#define ND 5
#define MAXDEG 64
#define NBLK_L 2048        // layer grid: wave = one node, 4 nodes/block

// xl / xr layout: [node][b=64][hc=16] fp16 (2 KB/row). h (final only): same, fp32.
// Wave = node, lane = b: every gather/row access is contiguous 2 KB per wave.

// ---------------- slot-table build ----------------

__global__ void k_fill0(int* __restrict__ cnt, int* __restrict__ slot) {
  int v = blockIdx.x*blockDim.x + threadIdx.x;   // 8192
  cnt[v] = 1;                                    // self-loop pre-seeded
  slot[v*MAXDEG] = v;
}

__global__ void k_fill(const int* __restrict__ nbr, int* __restrict__ cnt, int* __restrict__ slot) {
  int i = blockIdx.x*blockDim.x + threadIdx.x;   // 40960 edges
  int v = nbr[i];
  int pos = atomicAdd(&cnt[v], 1);
  slot[v*MAXDEG + pos] = i/ND;                   // src node u
}

// ---------------- t0: xl0 = x@Wl0, xr0 = x@Wr0 (both fp16; h never materialized) ----------------

__global__ void __launch_bounds__(256)
k_t0(const float* __restrict__ x, const float* __restrict__ Wl0, const float* __restrict__ Wr0,
     __half* __restrict__ xl0, __half* __restrict__ xr0) {
  int gid = blockIdx.x*blockDim.x + threadIdx.x;
  int n = gid >> 6;
  int b = gid & 63;
  const float4* src = (const float4*)(x + (((size_t)b*NNODES + n) << 4));
  float hv[16];
  #pragma unroll
  for (int q = 0; q < 4; ++q) *(float4*)(hv+4*q) = src[q];
  float yl[16], yr[16];
  #pragma unroll
  for (int j = 0; j < 16; ++j) { yl[j] = 0.f; yr[j] = 0.f; }
  #pragma unroll
  for (int f = 0; f < 16; ++f) {
    float hf = hv[f];
    #pragma unroll
    for (int j = 0; j < 16; ++j) {
      yl[j] = fmaf(hf, Wl0[f*16+j], yl[j]);
      yr[j] = fmaf(hf, Wr0[f*16+j], yr[j]);
    }
  }
  size_t idx = ((size_t)n << 10) + (b << 4);
  __half2 lh[8], rh[8];
  #pragma unroll
  for (int j = 0; j < 8; ++j) {
    lh[j] = __floats2half2_rn(yl[2*j], yl[2*j+1]);
    rh[j] = __floats2half2_rn(yr[2*j], yr[2*j+1]);
  }
  float4* ld = (float4*)(xl0 + idx);
  ld[0] = *(float4*)&lh[0]; ld[1] = *(float4*)&lh[4];
  float4* rd = (float4*)(xr0 + idx);
  rd[0] = *(float4*)&rh[0]; rd[1] = *(float4*)&rh[4];
}

// ---------------- fused GATv2 layer (no h between layers) ----------------
// Consumes xlin/xrin (fp16); produces xlout/xrout = o @ {WlNext,WrNext} (fp16).
// LAST: writes h (fp32) + per-block mean partials instead.

template<bool LAST>
__global__ void __launch_bounds__(256)
k_layer(const __half* __restrict__ xlin, const __half* __restrict__ xrin,
        __half* __restrict__ xlout, __half* __restrict__ xrout,
        const float* __restrict__ WlNext, const float* __restrict__ WrNext,
        const float* __restrict__ att, const float* __restrict__ bias,
        const int* __restrict__ cnt, const int* __restrict__ slot,
        float* __restrict__ h, float* __restrict__ meanpart) {
  __shared__ float msm[4096];                    // 16 KB, used in LAST only
  int gid = blockIdx.x*blockDim.x + threadIdx.x;
  int v = gid >> 6;
  int b = gid & 63;
  int w = threadIdx.x >> 6;
  size_t boff = (size_t)(b << 4);

  // own xr row (fp16 -> fp32)
  float xr[16];
  {
    const float4* rp = (const float4*)(xrin + ((size_t)v << 10) + boff);
    float4 r0 = rp[0], r1 = rp[1];
    const __half2* pa = (const __half2*)&r0;
    const __half2* pb = (const __half2*)&r1;
    #pragma unroll
    for (int q = 0; q < 4; ++q) { float2 f = __half22float2(pa[q]); xr[2*q] = f.x; xr[2*q+1] = f.y; }
    #pragma unroll
    for (int q = 0; q < 4; ++q) { float2 f = __half22float2(pb[q]); xr[8+2*q] = f.x; xr[8+2*q+1] = f.y; }
  }
  float aw[16];
  #pragma unroll
  for (int j = 0; j < 16; ++j) aw[j] = att[j];

  float s4[4] = {0.f, 0.f, 0.f, 0.f};
  float acc[16];
  #pragma unroll
  for (int j = 0; j < 16; ++j) acc[j] = 0.f;

  int deg = cnt[v];
  const int* sl = slot + v*MAXDEG;

  auto loadrow = [&](int u, float4& r0, float4& r1) {
    const float4* sp = (const float4*)(xlin + ((size_t)u << 10) + boff);
    r0 = sp[0]; r1 = sp[1];
  };
  auto process = [&](const float4& r0, const float4& r1) {
    float t[16];
    const __half2* pa = (const __half2*)&r0;
    const __half2* pb = (const __half2*)&r1;
    #pragma unroll
    for (int q = 0; q < 4; ++q) { float2 f = __half22float2(pa[q]); t[2*q] = f.x; t[2*q+1] = f.y; }
    #pragma unroll
    for (int q = 0; q < 4; ++q) { float2 f = __half22float2(pb[q]); t[8+2*q] = f.x; t[8+2*q+1] = f.y; }
    #pragma unroll
    for (int hh = 0; hh < 4; ++hh) {
      float lg = 0.f;
      #pragma unroll
      for (int c = 0; c < 4; ++c) {
        float z = t[hh*4+c] + xr[hh*4+c];
        z = (z >= 0.f) ? z : 0.2f*z;       // leaky_relu slope 0.2
        lg = fmaf(z, aw[hh*4+c], lg);
      }
      float p = __expf(lg);                // no max-rescale: logits bounded
      s4[hh] += p;
      #pragma unroll
      for (int c = 0; c < 4; ++c) acc[hh*4+c] = fmaf(p, t[hh*4+c], acc[hh*4+c]);
    }
  };

  // depth-3 software pipeline, explicit rotation (no dynamic register indexing)
  float4 a0, a1, b0, b1, c0, c1;
  loadrow(sl[0], a0, a1);
  if (deg > 1) loadrow(sl[1], b0, b1);
  if (deg > 2) loadrow(sl[2], c0, c1);
  int e = 0;
  for (; e+3 <= deg; e += 3) {
    process(a0, a1); if (e+3 < deg) loadrow(sl[e+3], a0, a1);
    process(b0, b1); if (e+4 < deg) loadrow(sl[e+4], b0, b1);
    process(c0, c1); if (e+5 < deg) loadrow(sl[e+5], c0, c1);
  }
  if (e < deg)   process(a0, a1);
  if (e+1 < deg) process(b0, b1);

  float o[16];
  #pragma unroll
  for (int hh = 0; hh < 4; ++hh) {
    float inv = 1.f / s4[hh];
    #pragma unroll
    for (int c = 0; c < 4; ++c) o[hh*4+c] = fmaf(acc[hh*4+c], inv, bias[hh*4+c]);
  }

  if (!LAST) {
    float yl[16], yr[16];
    #pragma unroll
    for (int j = 0; j < 16; ++j) { yl[j] = 0.f; yr[j] = 0.f; }
    #pragma unroll
    for (int f = 0; f < 16; ++f) {
      float of = o[f];
      #pragma unroll
      for (int j = 0; j < 16; ++j) {
        yl[j] = fmaf(of, WlNext[f*16+j], yl[j]);
        yr[j] = fmaf(of, WrNext[f*16+j], yr[j]);
      }
    }
    __half2 lh[8], rh[8];
    #pragma unroll
    for (int j = 0; j < 8; ++j) {
      lh[j] = __floats2half2_rn(yl[2*j], yl[2*j+1]);
      rh[j] = __floats2half2_rn(yr[2*j], yr[2*j+1]);
    }
    size_t idx = ((size_t)v << 10) + boff;
    float4* ld = (float4*)(xlout + idx);
    ld[0] = *(float4*)&lh[0]; ld[1] = *(float4*)&lh[4];
    float4* rd = (float4*)(xrout + idx);
    rd[0] = *(float4*)&rh[0]; rd[1] = *(float4*)&rh[4];
  } else {
    float4* hd = (float4*)(h + ((size_t)v << 10) + boff);
    #pragma unroll
    for (int q = 0; q < 4; ++q) hd[q] = *(float4*)(o+4*q);
    // per-block mean partials: msm[w][b][16] -> meanpart[block][b*16+hc]
    #pragma unroll
    for (int j = 0; j < 16; ++j) msm[(w << 10) + (b << 4) + j] = o[j];
    __syncthreads();
    for (int i = threadIdx.x; i < 1024; i += 256) {
      float s = msm[i] + msm[1024+i] + msm[2048+i] + msm[3072+i];
      meanpart[(size_t)blockIdx.x*1024 + i] = s;
    }
  }
}

// ---------------- fused tail: meanpart reduce + mean MLP + edge MLP ----------------

__global__ void __launch_bounds__(256)
k_tail(const float* __restrict__ h, const int* __restrict__ agent,
       const int* __restrict__ nbr, const float* __restrict__ meanpart,
       const float* __restrict__ Wg1, const float* __restrict__ bg1,
       const float* __restrict__ Wg2, const float* __restrict__ bg2,
       const float* __restrict__ We1, const float* __restrict__ be1,
       const float* __restrict__ We2, const float* __restrict__ be2,
       const float* __restrict__ We3, const float* __restrict__ be3,
       float* __restrict__ out) {
  int b = blockIdx.x;
  int t = threadIdx.x;                 // 256
  __shared__ float red[256];
  __shared__ float mean[16], g1[32], aggs[64];
  __shared__ float srcv[16];
  __shared__ float tgt[5][16];
  __shared__ float e1s[15][16];
  __shared__ float e2s[15][8];
  int an = agent[b];

  // reduce meanpart[p][b*16+hc] over p=0..NBLK_L-1
  {
    int hc = t & 15, grp = t >> 4;     // 16 groups x 128 partials
    float s = 0.f;
    for (int p = grp*128; p < grp*128+128; ++p) s += meanpart[(size_t)p*1024 + b*16 + hc];
    red[t] = s;
    __syncthreads();
    if (t < 16) {
      float m = 0.f;
      for (int g = 0; g < 16; ++g) m += red[g*16 + t];
      mean[t] = m * (1.0f/NNODES);
    }
  }
  if (t >= 64 && t < 80) srcv[t-64] = h[((size_t)an << 10) + (b << 4) + (t-64)];
  if (t >= 96 && t < 176) {
    int d = (t-96)/16, k = (t-96)%16;
    int nn = nbr[an*ND + d];
    tgt[d][k] = h[((size_t)nn << 10) + (b << 4) + k];
  }
  __syncthreads();
  if (t < 32) {
    float a = bg1[t];
    for (int f = 0; f < 16; ++f) a = fmaf(mean[f], Wg1[f*32+t], a);
    g1[t] = tanhf(a);
  }
  __syncthreads();
  if (t < 64) {
    float a = bg2[t];
    for (int f = 0; f < 32; ++f) a = fmaf(g1[f], Wg2[f*64+t], a);
    aggs[t] = tanhf(a);
  }
  __syncthreads();
  if (t < 240) {
    int j = t & 15, td = t >> 4;       // td = tk*5+d
    int tk = td/5, d = td%5;
    float a = be1[j];
    for (int k = 0; k < 16; ++k) a = fmaf(srcv[k],  We1[k*16+j],      a);
    a += We1[(16+tk)*16 + j];          // one-hot token rows 16..18
    for (int k = 0; k < 16; ++k) a = fmaf(tgt[d][k], We1[(19+k)*16+j], a);
    for (int k = 0; k < 64; ++k) a = fmaf(aggs[k],  We1[(35+k)*16+j], a);
    e1s[td][j] = tanhf(a);
  }
  __syncthreads();
  if (t < 120) {
    int j = t & 7, td = t >> 3;
    float a = be2[j];
    for (int k = 0; k < 16; ++k) a = fmaf(e1s[td][k], We2[k*8+j], a);
    e2s[td][j] = tanhf(a);
  }
  __syncthreads();
  if (t < 15) {
    float a = be3[0];
    for (int k = 0; k < 8; ++k) a = fmaf(e2s[t][k], We3[k], a);
    out[b*15 + t] = a;
  }
}

// ---------------- launch ----------------

extern "C" void kernel_launch(void* const* d_in, const int* in_sizes, int n_in,
                              void* d_out, int out_size, void* d_ws, size_t ws_size,
                              hipStream_t stream) {
  const float* x     = (const float*)d_in[0];
  const int*   agent = (const int*)  d_in[1];
  const int*   nbr   = (const int*)  d_in[2];
  const float* Wl    = (const float*)d_in[3];   // (4,16,4,4)
  const float* Wr    = (const float*)d_in[4];
  const float* att   = (const float*)d_in[5];   // (4,4,4)
  const float* bias  = (const float*)d_in[6];   // (4,16)
  const float* Wg1   = (const float*)d_in[7];
  const float* bg1   = (const float*)d_in[8];
  const float* Wg2   = (const float*)d_in[9];
  const float* bg2   = (const float*)d_in[10];
  const float* We1   = (const float*)d_in[11];
  const float* be1   = (const float*)d_in[12];
  const float* We2   = (const float*)d_in[13];
  const float* be2   = (const float*)d_in[14];
  const float* We3   = (const float*)d_in[15];
  const float* be3   = (const float*)d_in[16];
  float* out = (float*)d_out;

  char* ws = (char*)d_ws;
  size_t off = 0;
  auto alloc = [&](size_t bytes) -> void* {
    void* p = ws + off;
    off += (bytes + 255) & ~(size_t)255;
    return p;
  };
  const size_t HBYTES  = (size_t)NNODES*NB*16*sizeof(float);    // 32 MB
  const size_t XBYTES  = (size_t)NNODES*NB*16*sizeof(__half);   // 16 MB
  float*  h    = (float*)alloc(HBYTES);
  __half* xlA  = (__half*)alloc(XBYTES);
  __half* xlB  = (__half*)alloc(XBYTES);
  __half* xrA  = (__half*)alloc(XBYTES);
  __half* xrB  = (__half*)alloc(XBYTES);
  int* cnt     = (int*)alloc(NNODES*sizeof(int));
  int* slot    = (int*)alloc((size_t)NNODES*MAXDEG*sizeof(int));
  float* meanpart = (float*)alloc((size_t)NBLK_L*1024*sizeof(float));  // 8 MB

  k_fill0<<<NNODES/256, 256, 0, stream>>>(cnt, slot);
  k_fill<<<NNODES*ND/256, 256, 0, stream>>>(nbr, cnt, slot);

  k_t0<<<NBLK_L, 256, 0, stream>>>(x, Wl, Wr, xlA, xrA);

  k_layer<false><<<NBLK_L, 256, 0, stream>>>(xlA, xrA, xlB, xrB, Wl + 256, Wr + 256,
                                             att,      bias,      cnt, slot, nullptr, nullptr);
  k_layer<false><<<NBLK_L, 256, 0, stream>>>(xlB, xrB, xlA, xrA, Wl + 512, Wr + 512,
                                             att + 16, bias + 16, cnt, slot, nullptr, nullptr);
  k_layer<false><<<NBLK_L, 256, 0, stream>>>(xlA, xrA, xlB, xrB, Wl + 768, Wr + 768,
                                             att + 32, bias + 32, cnt, slot, nullptr, nullptr);
  k_layer<true ><<<NBLK_L, 256, 0, stream>>>(xlB, xrB, nullptr, nullptr, nullptr, nullptr,
                                             att + 48, bias + 48, cnt, slot, h, meanpart);

  k_tail<<<NB, 256, 0, stream>>>(h, agent, nbr, meanpart,
                                 Wg1, bg1, Wg2, bg2,
                                 We1, be1, We2, be2, We3, be3, out);
}

// Round 8
// 245.896 us; speedup vs baseline: 4.1830x; 1.0334x over previous
//
#include <hip/hip_runtime.h>
#include <hip/hip_fp16.h>
#include <cmath>

#define NNODES 8192
#define NB 64
#define ND 5
#define MAXDEG 64
#define NBLK_L 2048        // layer grid: wave = one node, 4 nodes/block

// xl / xr layout: [node][b=64][hc=16] fp16 (2 KB/row). h (final, sparse): fp16 same layout.
// Wave = node, lane = b: every gather/row access is contiguous 2 KB per wave.

// ---------------- init: cnt/slot self-loops + needed-mask (1 block) ----------------

__global__ void __launch_bounds__(1024)
k_init(const int* __restrict__ agent, const int* __restrict__ nbr,
       int* __restrict__ cnt, int* __restrict__ slot, int* __restrict__ needed) {
  int t = threadIdx.x;
  for (int v = t; v < NNODES; v += 1024) {
    cnt[v] = 1;                 // self-loop pre-seeded
    slot[v*MAXDEG] = v;
    needed[v] = 0;
  }
  __syncthreads();
  if (t < NB) {
    int an = agent[t];
    needed[an] = 1;
    #pragma unroll
    for (int d = 0; d < ND; ++d) needed[nbr[an*ND + d]] = 1;
  }
}

// ---------------- fused t0 + edge fill ----------------
// blocks [0,2048): t0 (xl0 = x@Wl0, xr0 = x@Wr0, fp16)
// blocks [2048,2208): slot-table fill for the 40960 edges

__global__ void __launch_bounds__(256)
k_t0fill(const float* __restrict__ x, const float* __restrict__ Wl0, const float* __restrict__ Wr0,
         __half* __restrict__ xl0, __half* __restrict__ xr0,
         const int* __restrict__ nbr, int* __restrict__ cnt, int* __restrict__ slot) {
  if (blockIdx.x >= NBLK_L) {
    int i = (blockIdx.x - NBLK_L)*256 + threadIdx.x;    // 40960 edges
    if (i < NNODES*ND) {
      int v = nbr[i];
      int pos = atomicAdd(&cnt[v], 1);
      slot[v*MAXDEG + pos] = i/ND;                      // src node u
    }
    return;
  }
  int gid = blockIdx.x*blockDim.x + threadIdx.x;
  int n = gid >> 6;
  int b = gid & 63;
  const float4* src = (const float4*)(x + (((size_t)b*NNODES + n) << 4));
  float hv[16];
  #pragma unroll
  for (int q = 0; q < 4; ++q) *(float4*)(hv+4*q) = src[q];
  float yl[16], yr[16];
  #pragma unroll
  for (int j = 0; j < 16; ++j) { yl[j] = 0.f; yr[j] = 0.f; }
  #pragma unroll
  for (int f = 0; f < 16; ++f) {
    float hf = hv[f];
    #pragma unroll
    for (int j = 0; j < 16; ++j) {
      yl[j] = fmaf(hf, Wl0[f*16+j], yl[j]);
      yr[j] = fmaf(hf, Wr0[f*16+j], yr[j]);
    }
  }
  size_t idx = ((size_t)n << 10) + (b << 4);
  __half2 lh[8], rh[8];
  #pragma unroll
  for (int j = 0; j < 8; ++j) {
    lh[j] = __floats2half2_rn(yl[2*j], yl[2*j+1]);
    rh[j] = __floats2half2_rn(yr[2*j], yr[2*j+1]);
  }
  float4* ld = (float4*)(xl0 + idx);
  ld[0] = *(float4*)&lh[0]; ld[1] = *(float4*)&lh[4];
  float4* rd = (float4*)(xr0 + idx);
  rd[0] = *(float4*)&rh[0]; rd[1] = *(float4*)&rh[4];
}

// ---------------- fused GATv2 layer ----------------
// Prefetch-all-min(deg,6) straight-line (deg is wave-uniform -> no divergence),
// remainder loop for deg>6. LAST: sparse fp16 h + per-block mean partials.

template<bool LAST>
__global__ void __launch_bounds__(256)
k_layer(const __half* __restrict__ xlin, const __half* __restrict__ xrin,
        __half* __restrict__ xlout, __half* __restrict__ xrout,
        const float* __restrict__ WlNext, const float* __restrict__ WrNext,
        const float* __restrict__ att, const float* __restrict__ bias,
        const int* __restrict__ cnt, const int* __restrict__ slot,
        const int* __restrict__ needed, __half* __restrict__ h,
        float* __restrict__ meanpart) {
  __shared__ float msm[4096];                    // 16 KB, used in LAST only
  int gid = blockIdx.x*blockDim.x + threadIdx.x;
  int v = gid >> 6;
  int b = gid & 63;
  int w = threadIdx.x >> 6;
  size_t boff = (size_t)(b << 4);

  // own xr row (fp16 -> fp32)
  float xr[16];
  {
    const float4* rp = (const float4*)(xrin + ((size_t)v << 10) + boff);
    float4 r0 = rp[0], r1 = rp[1];
    const __half2* pa = (const __half2*)&r0;
    const __half2* pb = (const __half2*)&r1;
    #pragma unroll
    for (int q = 0; q < 4; ++q) { float2 f = __half22float2(pa[q]); xr[2*q] = f.x; xr[2*q+1] = f.y; }
    #pragma unroll
    for (int q = 0; q < 4; ++q) { float2 f = __half22float2(pb[q]); xr[8+2*q] = f.x; xr[8+2*q+1] = f.y; }
  }
  float aw[16];
  #pragma unroll
  for (int j = 0; j < 16; ++j) aw[j] = att[j];

  float s4[4] = {0.f, 0.f, 0.f, 0.f};
  float acc[16];
  #pragma unroll
  for (int j = 0; j < 16; ++j) acc[j] = 0.f;

  int deg = cnt[v];
  const int* sl = slot + v*MAXDEG;

  auto loadrow = [&](int u, float4& r0, float4& r1) {
    const float4* sp = (const float4*)(xlin + ((size_t)u << 10) + boff);
    r0 = sp[0]; r1 = sp[1];
  };
  auto process = [&](const float4& r0, const float4& r1) {
    float t[16];
    const __half2* pa = (const __half2*)&r0;
    const __half2* pb = (const __half2*)&r1;
    #pragma unroll
    for (int q = 0; q < 4; ++q) { float2 f = __half22float2(pa[q]); t[2*q] = f.x; t[2*q+1] = f.y; }
    #pragma unroll
    for (int q = 0; q < 4; ++q) { float2 f = __half22float2(pb[q]); t[8+2*q] = f.x; t[8+2*q+1] = f.y; }
    #pragma unroll
    for (int hh = 0; hh < 4; ++hh) {
      float lg = 0.f;
      #pragma unroll
      for (int c = 0; c < 4; ++c) {
        float z = t[hh*4+c] + xr[hh*4+c];
        z = (z >= 0.f) ? z : 0.2f*z;       // leaky_relu slope 0.2
        lg = fmaf(z, aw[hh*4+c], lg);
      }
      float p = __expf(lg);                // no max-rescale: logits bounded
      s4[hh] += p;
      #pragma unroll
      for (int c = 0; c < 4; ++c) acc[hh*4+c] = fmaf(p, t[hh*4+c], acc[hh*4+c]);
    }
  };

  // straight-line prefetch of min(deg,6) rows; all deg-branches are wave-uniform
  float4 r00,r01, r10,r11, r20,r21, r30,r31, r40,r41, r50,r51, p0,p1;
  loadrow(sl[0], r00, r01);
  if (deg > 1) loadrow(sl[1], r10, r11);
  if (deg > 2) loadrow(sl[2], r20, r21);
  if (deg > 3) loadrow(sl[3], r30, r31);
  if (deg > 4) loadrow(sl[4], r40, r41);
  if (deg > 5) loadrow(sl[5], r50, r51);
  if (deg > 6) loadrow(sl[6], p0, p1);     // head of remainder
  process(r00, r01);
  if (deg > 1) process(r10, r11);
  if (deg > 2) process(r20, r21);
  if (deg > 3) process(r30, r31);
  if (deg > 4) process(r40, r41);
  if (deg > 5) process(r50, r51);
  for (int e = 6; e < deg; ++e) {
    float4 c0 = p0, c1 = p1;
    if (e+1 < deg) loadrow(sl[e+1], p0, p1);
    process(c0, c1);
  }

  float o[16];
  #pragma unroll
  for (int hh = 0; hh < 4; ++hh) {
    float inv = 1.f / s4[hh];
    #pragma unroll
    for (int c = 0; c < 4; ++c) o[hh*4+c] = fmaf(acc[hh*4+c], inv, bias[hh*4+c]);
  }

  if (!LAST) {
    float yl[16], yr[16];
    #pragma unroll
    for (int j = 0; j < 16; ++j) { yl[j] = 0.f; yr[j] = 0.f; }
    #pragma unroll
    for (int f = 0; f < 16; ++f) {
      float of = o[f];
      #pragma unroll
      for (int j = 0; j < 16; ++j) {
        yl[j] = fmaf(of, WlNext[f*16+j], yl[j]);
        yr[j] = fmaf(of, WrNext[f*16+j], yr[j]);
      }
    }
    __half2 lh[8], rh[8];
    #pragma unroll
    for (int j = 0; j < 8; ++j) {
      lh[j] = __floats2half2_rn(yl[2*j], yl[2*j+1]);
      rh[j] = __floats2half2_rn(yr[2*j], yr[2*j+1]);
    }
    size_t idx = ((size_t)v << 10) + boff;
    float4* ld = (float4*)(xlout + idx);
    ld[0] = *(float4*)&lh[0]; ld[1] = *(float4*)&lh[4];
    float4* rd = (float4*)(xrout + idx);
    rd[0] = *(float4*)&rh[0]; rd[1] = *(float4*)&rh[4];
  } else {
    if (needed[v]) {                       // sparse h: only agent/neighbor rows
      __half2 oh[8];
      #pragma unroll
      for (int j = 0; j < 8; ++j) oh[j] = __floats2half2_rn(o[2*j], o[2*j+1]);
      float4* hd = (float4*)(h + ((size_t)v << 10) + boff);
      hd[0] = *(float4*)&oh[0]; hd[1] = *(float4*)&oh[4];
    }
    // per-block mean partials: msm[w][b][16] -> meanpart[block][b*16+hc]
    #pragma unroll
    for (int j = 0; j < 16; ++j) msm[(w << 10) + (b << 4) + j] = o[j];
    __syncthreads();
    for (int i = threadIdx.x; i < 1024; i += 256) {
      float s = msm[i] + msm[1024+i] + msm[2048+i] + msm[3072+i];
      meanpart[(size_t)blockIdx.x*1024 + i] = s;
    }
  }
}

// ---------------- fused tail: meanpart reduce + mean MLP + edge MLP ----------------

__global__ void __launch_bounds__(256)
k_tail(const __half* __restrict__ h, const int* __restrict__ agent,
       const int* __restrict__ nbr, const float* __restrict__ meanpart,
       const float* __restrict__ Wg1, const float* __restrict__ bg1,
       const float* __restrict__ Wg2, const float* __restrict__ bg2,
       const float* __restrict__ We1, const float* __restrict__ be1,
       const float* __restrict__ We2, const float* __restrict__ be2,
       const float* __restrict__ We3, const float* __restrict__ be3,
       float* __restrict__ out) {
  int b = blockIdx.x;
  int t = threadIdx.x;                 // 256
  __shared__ float red[256];
  __shared__ float mean[16], g1[32], aggs[64];
  __shared__ float srcv[16];
  __shared__ float tgt[5][16];
  __shared__ float e1s[15][16];
  __shared__ float e2s[15][8];
  int an = agent[b];

  // reduce meanpart[p][b*16+hc] over p=0..NBLK_L-1
  {
    int hc = t & 15, grp = t >> 4;     // 16 groups x 128 partials
    float s = 0.f;
    for (int p = grp*128; p < grp*128+128; ++p) s += meanpart[(size_t)p*1024 + b*16 + hc];
    red[t] = s;
    __syncthreads();
    if (t < 16) {
      float m = 0.f;
      for (int g = 0; g < 16; ++g) m += red[g*16 + t];
      mean[t] = m * (1.0f/NNODES);
    }
  }
  if (t >= 64 && t < 80) srcv[t-64] = __half2float(h[((size_t)an << 10) + (b << 4) + (t-64)]);
  if (t >= 96 && t < 176) {
    int d = (t-96)/16, k = (t-96)%16;
    int nn = nbr[an*ND + d];
    tgt[d][k] = __half2float(h[((size_t)nn << 10) + (b << 4) + k]);
  }
  __syncthreads();
  if (t < 32) {
    float a = bg1[t];
    for (int f = 0; f < 16; ++f) a = fmaf(mean[f], Wg1[f*32+t], a);
    g1[t] = tanhf(a);
  }
  __syncthreads();
  if (t < 64) {
    float a = bg2[t];
    for (int f = 0; f < 32; ++f) a = fmaf(g1[f], Wg2[f*64+t], a);
    aggs[t] = tanhf(a);
  }
  __syncthreads();
  if (t < 240) {
    int j = t & 15, td = t >> 4;       // td = tk*5+d
    int tk = td/5, d = td%5;
    float a = be1[j];
    for (int k = 0; k < 16; ++k) a = fmaf(srcv[k],  We1[k*16+j],      a);
    a += We1[(16+tk)*16 + j];          // one-hot token rows 16..18
    for (int k = 0; k < 16; ++k) a = fmaf(tgt[d][k], We1[(19+k)*16+j], a);
    for (int k = 0; k < 64; ++k) a = fmaf(aggs[k],  We1[(35+k)*16+j], a);
    e1s[td][j] = tanhf(a);
  }
  __syncthreads();
  if (t < 120) {
    int j = t & 7, td = t >> 3;
    float a = be2[j];
    for (int k = 0; k < 16; ++k) a = fmaf(e1s[td][k], We2[k*8+j], a);
    e2s[td][j] = tanhf(a);
  }
  __syncthreads();
  if (t < 15) {
    float a = be3[0];
    for (int k = 0; k < 8; ++k) a = fmaf(e2s[t][k], We3[k], a);
    out[b*15 + t] = a;
  }
}

// ---------------- launch ----------------

extern "C" void kernel_launch(void* const* d_in, const int* in_sizes, int n_in,
                              void* d_out, int out_size, void* d_ws, size_t ws_size,
                              hipStream_t stream) {
  const float* x     = (const float*)d_in[0];
  const int*   agent = (const int*)  d_in[1];
  const int*   nbr   = (const int*)  d_in[2];
  const float* Wl    = (const float*)d_in[3];   // (4,16,4,4)
  const float* Wr    = (const float*)d_in[4];
  const float* att   = (const float*)d_in[5];   // (4,4,4)
  const float* bias  = (const float*)d_in[6];   // (4,16)
  const float* Wg1   = (const float*)d_in[7];
  const float* bg1   = (const float*)d_in[8];
  const float* Wg2   = (const float*)d_in[9];
  const float* bg2   = (const float*)d_in[10];
  const float* We1   = (const float*)d_in[11];
  const float* be1   = (const float*)d_in[12];
  const float* We2   = (const float*)d_in[13];
  const float* be2   = (const float*)d_in[14];
  const float* We3   = (const float*)d_in[15];
  const float* be3   = (const float*)d_in[16];
  float* out = (float*)d_out;

  char* ws = (char*)d_ws;
  size_t off = 0;
  auto alloc = [&](size_t bytes) -> void* {
    void* p = ws + off;
    off += (bytes + 255) & ~(size_t)255;
    return p;
  };
  const size_t XBYTES  = (size_t)NNODES*NB*16*sizeof(__half);   // 16 MB
  __half* h    = (__half*)alloc(XBYTES);
  __half* xlA  = (__half*)alloc(XBYTES);
  __half* xlB  = (__half*)alloc(XBYTES);
  __half* xrA  = (__half*)alloc(XBYTES);
  __half* xrB  = (__half*)alloc(XBYTES);
  int* cnt     = (int*)alloc(NNODES*sizeof(int));
  int* needed  = (int*)alloc(NNODES*sizeof(int));
  int* slot    = (int*)alloc((size_t)NNODES*MAXDEG*sizeof(int));
  float* meanpart = (float*)alloc((size_t)NBLK_L*1024*sizeof(float));  // 8 MB

  k_init<<<1, 1024, 0, stream>>>(agent, nbr, cnt, slot, needed);
  k_t0fill<<<NBLK_L + NNODES*ND/256, 256, 0, stream>>>(x, Wl, Wr, xlA, xrA, nbr, cnt, slot);

  k_layer<false><<<NBLK_L, 256, 0, stream>>>(xlA, xrA, xlB, xrB, Wl + 256, Wr + 256,
                                             att,      bias,      cnt, slot, needed, nullptr, nullptr);
  k_layer<false><<<NBLK_L, 256, 0, stream>>>(xlB, xrB, xlA, xrA, Wl + 512, Wr + 512,
                                             att + 16, bias + 16, cnt, slot, needed, nullptr, nullptr);
  k_layer<false><<<NBLK_L, 256, 0, stream>>>(xlA, xrA, xlB, xrB, Wl + 768, Wr + 768,
                                             att + 32, bias + 32, cnt, slot, needed, nullptr, nullptr);
  k_layer<true ><<<NBLK_L, 256, 0, stream>>>(xlB, xrB, nullptr, nullptr, nullptr, nullptr,
                                             att + 48, bias + 48, cnt, slot, needed, h, meanpart);

  k_tail<<<NB, 256, 0, stream>>>(h, agent, nbr, meanpart,
                                 Wg1, bg1, Wg2, bg2,
                                 We1, be1, We2, be2, We3, be3, out);
}